// Round 6
// baseline (197.004 us; speedup 1.0000x reference)
//
#include <hip/hip_runtime.h>

typedef __bf16 bf16x8 __attribute__((ext_vector_type(8)));
typedef float f32x4 __attribute__((ext_vector_type(4)));
typedef float f32x16 __attribute__((ext_vector_type(16)));
typedef unsigned short u16;
typedef unsigned int u32;
typedef u16 u16x4 __attribute__((ext_vector_type(4)));
typedef u32 u32x4 __attribute__((ext_vector_type(4)));

__device__ __forceinline__ u16 f2bf(float f) {
    union { float f; u32 u; } x{f};
    u32 r = x.u + 0x7FFFu + ((x.u >> 16) & 1u);  // RNE
    return (u16)(r >> 16);
}

__device__ __forceinline__ float ex2(float x) {
#if __has_builtin(__builtin_amdgcn_exp2f)
    return __builtin_amdgcn_exp2f(x);
#else
    return __expf(x * 0.6931471805599453f);
#endif
}

// round-half-up bf16 (inputs >= 0), packed pair into u32
__device__ __forceinline__ u32 pkbf(float a, float b) {
    union { float f; u32 u; } ca{a}, cb{b};
    return ((ca.u + 0x8000u) >> 16) | (((cb.u + 0x8000u) >> 16) << 16);
}

// async global->LDS, 16B per lane; LDS dest = wave-uniform base + lane*16
#define GLD16(g, l)                                                            \
    __builtin_amdgcn_global_load_lds(                                          \
        (const __attribute__((address_space(1))) u32*)(g),                     \
        (__attribute__((address_space(3))) u32*)(l), 16, 0, 0)

// ---------------------------------------------------------------------------
// Elementwise fp32 -> bf16 convert (x)
// ---------------------------------------------------------------------------
__global__ void convert_bf16(const float* __restrict__ src, u16* __restrict__ dst, int n4) {
    int i = blockIdx.x * blockDim.x + threadIdx.x;
    if (i < n4) {
        float4 f = *(const float4*)(src + (size_t)i * 4);
        u16x4 u = { f2bf(f.x), f2bf(f.y), f2bf(f.z), f2bf(f.w) };
        *(u16x4*)(dst + (size_t)i * 4) = u;
    }
}

// ---------------------------------------------------------------------------
// Both weight transposes in one kernel.
// ---------------------------------------------------------------------------
__global__ __launch_bounds__(256) void prep_weights(
    const float* __restrict__ wq, const float* __restrict__ wp,
    u16* __restrict__ WqT, u16* __restrict__ WpT)
{
    __shared__ u16 tile[32][33];
    int id = blockIdx.x;
    const float* src; u16* dst; int R, C, bx, by;
    if (id < 1728) { src = wq; dst = WqT; R = 768; C = 2304; bx = (id % 72) * 32; by = (id / 72) * 32; }
    else { id -= 1728; src = wp; dst = WpT; R = 768; C = 768; bx = (id % 24) * 32; by = (id / 24) * 32; }
    int x = threadIdx.x & 31, y = threadIdx.x >> 5;
    #pragma unroll
    for (int i = 0; i < 32; i += 8)
        tile[y + i][x] = f2bf(src[(size_t)(by + y + i) * C + bx + x]);
    __syncthreads();
    #pragma unroll
    for (int i = 0; i < 32; i += 8)
        dst[(size_t)(bx + y + i) * R + by + x] = tile[x][y + i];
}

// ---------------------------------------------------------------------------
// QKV GEMM, R6: 256x128 tile, 512 threads / 8 waves (4M x 2N, per-wave
// 64x64), 16x16x32 MFMA with the MEASURED conflict-free XOR-granule read
// pattern (R5's 32x32 pattern cost 4 conflict-cycles per ds_read_b128).
// 3-buffer LDS (144 KiB), stage-ahead-2, counted s_waitcnt vmcnt(6) at each
// tile boundary (never 0 in steady state). NEW: m201-style fine phase
// interleave -- each K-tile is 2 phases, each {8 ds_reads (one k-half,
// consumed immediately) || 3 staging loads -> s_barrier -> setprio+16 MFMA
// -> s_barrier}. Short fragment live ranges (no R1-style spills).
// Grid 576 = 32 row-tiles x 18 col-tiles, XCD-chunked bijectively (8*72).
// V-section (bn>=1536) swaps MFMA operands -> Vt scatter (R0-proven).
// ---------------------------------------------------------------------------
#define MFMA16 __builtin_amdgcn_mfma_f32_16x16x32_bf16

// staging split across the two phases: P0 = A rows {0,8,16}, P1 = A row 24 + B rows {0,8}
#define STG_P0(tt)                                                              \
    {                                                                           \
        u16* ab_ = &lds[((tt) % 3) * 24576];                                    \
        GLD16(Ap + (tt) * 64 + (size_t)0 * 8 * K, &ab_[(wave * 32 + 0)  * 64]); \
        GLD16(Ap + (tt) * 64 + (size_t)1 * 8 * K, &ab_[(wave * 32 + 8)  * 64]); \
        GLD16(Ap + (tt) * 64 + (size_t)2 * 8 * K, &ab_[(wave * 32 + 16) * 64]); \
    }
#define STG_P1(tt)                                                              \
    {                                                                           \
        u16* ab_ = &lds[((tt) % 3) * 24576];                                    \
        GLD16(Ap + (tt) * 64 + (size_t)3 * 8 * K, &ab_[(wave * 32 + 24) * 64]); \
        GLD16(Bp + (tt) * 64 + (size_t)0 * 8 * K, &ab_[16384 + (wave * 16 + 0) * 64]); \
        GLD16(Bp + (tt) * 64 + (size_t)1 * 8 * K, &ab_[16384 + (wave * 16 + 8) * 64]); \
    }

template <int K>
__global__ __launch_bounds__(512, 1) void gemm_qkv(
    const u16* __restrict__ A,
    const u16* __restrict__ Wt,
    u16* __restrict__ QKV,
    u16* __restrict__ Vt,
    float qscale)
{
    extern __shared__ __align__(16) u16 lds[];   // 3 * (256*64 + 128*64) u16 = 144 KiB

    constexpr int NT = K / 64;   // 12 K-tiles

    int tid = threadIdx.x;
    int wave = tid >> 6, lane = tid & 63;
    int quad = lane >> 4, l16 = lane & 15;
    int wm = (wave >> 1) * 64;      // 4 M-waves: 0,64,128,192
    int wn = (wave & 1) * 64;       // 2 N-waves: 0,64

    int id = blockIdx.x;
    int lin = (id & 7) * 72 + (id >> 3);    // XCD-chunked, bijective (576 = 8*72)
    int bm = (lin / 18) * 256;              // 32 row-tiles
    int bn = (lin % 18) * 128;              // 18 col-tiles
    bool vsec = (bn >= 1536);

    f32x4 acc[4][4] = {};

    int srow = lane >> 3;
    int scg = ((lane & 7) ^ srow) * 8;
    const u16* Ap = A  + (size_t)(bm + wave * 32 + srow) * K + scg;
    const u16* Bp = Wt + (size_t)(bn + wave * 16 + srow) * K + scg;

    int fg0 = ((0 * 4 + quad) ^ (l16 & 7)) * 8;
    int fg1 = ((1 * 4 + quad) ^ (l16 & 7)) * 8;

    // prologue: stage tiles 0,1 (12 loads/thread); wait tile 0 (6 in flight)
    STG_P0(0); STG_P1(0);
    STG_P0(1); STG_P1(1);
    asm volatile("s_waitcnt vmcnt(6)" ::: "memory");
    __builtin_amdgcn_s_barrier();

    #pragma unroll 3
    for (int t = 0; t < NT; ++t) {
        const u16* Ab = &lds[(t % 3) * 24576];
        const u16* Bb = Ab + 16384;

        // ---- phase 0 (k-half 0): 8 ds_reads + 3 staging -> bar -> 16 MFMA -> bar
        {
            bf16x8 af[4], bfr[4];
            #pragma unroll
            for (int i = 0; i < 4; i++) {
                af[i]  = *(const bf16x8*)&Ab[(wm + i * 16 + l16) * 64 + fg0];
                bfr[i] = *(const bf16x8*)&Bb[(wn + i * 16 + l16) * 64 + fg0];
            }
            if (t + 2 < NT) STG_P0(t + 2);
            __builtin_amdgcn_s_barrier();
            __builtin_amdgcn_s_setprio(1);
            if (!vsec) {
                #pragma unroll
                for (int mi = 0; mi < 4; mi++)
                    #pragma unroll
                    for (int ni = 0; ni < 4; ni++)
                        acc[mi][ni] = MFMA16(af[mi], bfr[ni], acc[mi][ni], 0, 0, 0);
            } else {
                #pragma unroll
                for (int mi = 0; mi < 4; mi++)
                    #pragma unroll
                    for (int ni = 0; ni < 4; ni++)
                        acc[mi][ni] = MFMA16(bfr[ni], af[mi], acc[mi][ni], 0, 0, 0);
            }
            __builtin_amdgcn_s_setprio(0);
            __builtin_amdgcn_s_barrier();
        }

        // ---- phase 1 (k-half 1): 8 ds_reads + 3 staging -> bar -> 16 MFMA -> boundary
        {
            bf16x8 af[4], bfr[4];
            #pragma unroll
            for (int i = 0; i < 4; i++) {
                af[i]  = *(const bf16x8*)&Ab[(wm + i * 16 + l16) * 64 + fg1];
                bfr[i] = *(const bf16x8*)&Bb[(wn + i * 16 + l16) * 64 + fg1];
            }
            if (t + 2 < NT) STG_P1(t + 2);
            __builtin_amdgcn_s_barrier();
            __builtin_amdgcn_s_setprio(1);
            if (!vsec) {
                #pragma unroll
                for (int mi = 0; mi < 4; mi++)
                    #pragma unroll
                    for (int ni = 0; ni < 4; ni++)
                        acc[mi][ni] = MFMA16(af[mi], bfr[ni], acc[mi][ni], 0, 0, 0);
            } else {
                #pragma unroll
                for (int mi = 0; mi < 4; mi++)
                    #pragma unroll
                    for (int ni = 0; ni < 4; ni++)
                        acc[mi][ni] = MFMA16(bfr[ni], af[mi], acc[mi][ni], 0, 0, 0);
            }
            __builtin_amdgcn_s_setprio(0);
            // boundary: t+1's 6 loads must be done; t+2's 6 stay in flight
            if (t + 1 < NT) {
                if (t + 2 < NT) { asm volatile("s_waitcnt vmcnt(6)" ::: "memory"); }
                else            { asm volatile("s_waitcnt vmcnt(0)" ::: "memory"); }
            }
            __builtin_amdgcn_s_barrier();
        }
    }

    if (!vsec) {
        float sc = (bn < 768) ? qscale : 1.0f;   // col-tile is uniformly Q or K
        #pragma unroll
        for (int mi = 0; mi < 4; mi++) {
            #pragma unroll
            for (int ni = 0; ni < 4; ni++) {
                #pragma unroll
                for (int rg = 0; rg < 4; rg++) {
                    int row = bm + wm + mi * 16 + quad * 4 + rg;
                    int col = bn + wn + ni * 16 + l16;
                    QKV[(size_t)row * 2304 + col] = f2bf(acc[mi][ni][rg] * sc);
                }
            }
        }
    } else {
        #pragma unroll
        for (int mi = 0; mi < 4; mi++) {
            #pragma unroll
            for (int ni = 0; ni < 4; ni++) {
                #pragma unroll
                for (int rg = 0; rg < 4; rg++) {
                    int d = (bn - 1536) + wn + ni * 16 + quad * 4 + rg;
                    int ng = bm + wm + mi * 16 + l16;
                    int b = ng >> 10, n = ng & 1023, h = d >> 6;
                    Vt[((size_t)(b * 12 + h) * 64 + (d & 63)) * 1024 + n] = f2bf(acc[mi][ni][rg]);
                }
            }
        }
    }
}

#undef STG_P0
#undef STG_P1

// ---------------------------------------------------------------------------
// Output projection GEMM: R0-proven single-buffer 16x16 form (zero-conflict).
// ---------------------------------------------------------------------------
template <int K>
__global__ __launch_bounds__(256) void gemm_proj(
    const u16* __restrict__ A,
    const u16* __restrict__ Bt,
    float* __restrict__ Cp,
    const float* __restrict__ bias,
    int M, int N)
{
    __shared__ __align__(16) u16 As[128 * 64];
    __shared__ __align__(16) u16 Bs[128 * 64];

    int tid = threadIdx.x;
    int wave = tid >> 6, lane = tid & 63;
    int quad = lane >> 4, l16 = lane & 15;
    int wm = (wave >> 1) * 64, wn = (wave & 1) * 64;
    int bm = blockIdx.y * 128, bn = blockIdx.x * 128;

    f32x4 acc[4][4] = {};

    int srow = lane >> 3;
    int scg = ((lane & 7) ^ srow) * 8;
    const u16* Ap = A + (size_t)(bm + wave * 32 + srow) * K + scg;
    const u16* Bp = Bt + (size_t)(bn + wave * 32 + srow) * K + scg;

    int fg0 = (((0 * 4 + quad) ^ (l16 & 7)) * 8);
    int fg1 = (((1 * 4 + quad) ^ (l16 & 7)) * 8);

    for (int k0 = 0; k0 < K; k0 += 64) {
        #pragma unroll
        for (int j = 0; j < 4; j++) {
            GLD16(Ap + k0 + (size_t)j * 8 * K, &As[(wave * 32 + j * 8) * 64]);
            GLD16(Bp + k0 + (size_t)j * 8 * K, &Bs[(wave * 32 + j * 8) * 64]);
        }
        __syncthreads();

        #pragma unroll
        for (int h = 0; h < 2; h++) {
            int fg = h ? fg1 : fg0;
            bf16x8 af[4], bfr[4];
            #pragma unroll
            for (int i = 0; i < 4; i++) {
                af[i]  = *(const bf16x8*)&As[(wm + i * 16 + l16) * 64 + fg];
                bfr[i] = *(const bf16x8*)&Bs[(wn + i * 16 + l16) * 64 + fg];
            }
            #pragma unroll
            for (int mi = 0; mi < 4; mi++)
                #pragma unroll
                for (int ni = 0; ni < 4; ni++)
                    acc[mi][ni] = __builtin_amdgcn_mfma_f32_16x16x32_bf16(af[mi], bfr[ni], acc[mi][ni], 0, 0, 0);
        }
        __syncthreads();
    }

    #pragma unroll
    for (int mi = 0; mi < 4; mi++) {
        #pragma unroll
        for (int ni = 0; ni < 4; ni++) {
            #pragma unroll
            for (int rg = 0; rg < 4; rg++) {
                int row = bm + wm + mi * 16 + quad * 4 + rg;
                int col = bn + wn + ni * 16 + l16;
                Cp[(size_t)row * N + col] = acc[mi][ni][rg] + bias[col];
            }
        }
    }
}

// ---------------------------------------------------------------------------
// Flash attention v4 (unchanged): 32x32x16 MFMA, no P LDS roundtrip.
// ---------------------------------------------------------------------------
__global__ __launch_bounds__(256, 4) void attn_kernel(
    const u16* __restrict__ qkv,
    const u16* __restrict__ Vt,
    u16* __restrict__ ctx)
{
    __shared__ __align__(16) u16 Ks[2][4096];   // 2 x 64key x 64d (swizzled)
    __shared__ __align__(16) u16 Vs[2][4096];   // 2 x 64d x 64key (swizzled)

    int qt = blockIdx.x;            // 0..7 (128 q rows per block)
    int bh = blockIdx.y;            // 0..95
    int b = bh / 12, h = bh % 12;
    int tid = threadIdx.x;
    int wave = tid >> 6, lane = tid & 63;
    int l32 = lane & 31, half = lane >> 5;

    const u16* qbase = qkv + (size_t)(b * 1024 + qt * 128 + wave * 32 + l32) * 2304 + h * 64;
    bf16x8 qa[4];
    #pragma unroll
    for (int ks = 0; ks < 4; ks++)
        qa[ks] = *(const bf16x8*)(qbase + ks * 16 + half * 8);

    int srow = lane >> 3;
    int scol = (lane & 7) ^ srow;
    const u16* kA = qkv + (size_t)(b * 1024 + wave * 16 + srow) * 2304 + 768 + h * 64 + scol * 8;
    const u16* vA = Vt + ((size_t)bh * 64 + wave * 16 + srow) * 1024 + scol * 8;

    bf16x8 ones;
    #pragma unroll
    for (int j = 0; j < 8; j++) ((u16*)&ones)[j] = 0x3F80;  // bf16 1.0

    f32x16 o0 = {}, o1 = {}, lsum = {};

    int fgo[4];
    #pragma unroll
    for (int ks = 0; ks < 4; ks++)
        fgo[ks] = (((ks * 2 + half) ^ (lane & 7)) * 8);

    {
        GLD16(kA,            &Ks[0][(wave * 2 + 0) * 512]);
        GLD16(kA + 8 * 2304, &Ks[0][(wave * 2 + 1) * 512]);
        GLD16(vA,            &Vs[0][(wave * 2 + 0) * 512]);
        GLD16(vA + 8 * 1024, &Vs[0][(wave * 2 + 1) * 512]);
    }

    #pragma unroll 2
    for (int kt = 0; kt < 16; kt++) {
        int buf = kt & 1;
        __syncthreads();   // drains vmcnt(0): buf is populated

        if (kt < 15) {
            const u16* k0 = kA + (size_t)(kt + 1) * (64 * 2304);
            const u16* v0 = vA + (size_t)(kt + 1) * 64;
            GLD16(k0,            &Ks[buf ^ 1][(wave * 2 + 0) * 512]);
            GLD16(k0 + 8 * 2304, &Ks[buf ^ 1][(wave * 2 + 1) * 512]);
            GLD16(v0,            &Vs[buf ^ 1][(wave * 2 + 0) * 512]);
            GLD16(v0 + 8 * 1024, &Vs[buf ^ 1][(wave * 2 + 1) * 512]);
        }

        f32x16 st0 = {}, st1 = {};
        #pragma unroll
        for (int ks = 0; ks < 4; ks++) {
            bf16x8 kf0 = *(const bf16x8*)&Ks[buf][(l32)      * 64 + fgo[ks]];
            bf16x8 kf1 = *(const bf16x8*)&Ks[buf][(32 + l32) * 64 + fgo[ks]];
            st0 = __builtin_amdgcn_mfma_f32_32x32x16_bf16(kf0, qa[ks], st0, 0, 0, 0);
            st1 = __builtin_amdgcn_mfma_f32_32x32x16_bf16(kf1, qa[ks], st1, 0, 0, 0);
        }

        bf16x8 pf[4];
        #pragma unroll
        for (int t = 0; t < 2; t++) {
            u32 pk[8];
            #pragma unroll
            for (int g = 0; g < 4; g++) {
                float p0 = ex2(t ? st1[4 * g + 0] : st0[4 * g + 0]);
                float p1 = ex2(t ? st1[4 * g + 1] : st0[4 * g + 1]);
                float p2 = ex2(t ? st1[4 * g + 2] : st0[4 * g + 2]);
                float p3 = ex2(t ? st1[4 * g + 3] : st0[4 * g + 3]);
                pk[2 * g + 0] = pkbf(p0, p1);
                pk[2 * g + 1] = pkbf(p2, p3);
            }
            u32 rA0 = __shfl_xor(half ? pk[0] : pk[2], 32);
            u32 rA1 = __shfl_xor(half ? pk[1] : pk[3], 32);
            u32 rB0 = __shfl_xor(half ? pk[4] : pk[6], 32);
            u32 rB1 = __shfl_xor(half ? pk[5] : pk[7], 32);
            u32x4 f0 = { half ? rA0 : pk[0], half ? rA1 : pk[1],
                         half ? pk[2] : rA0, half ? pk[3] : rA1 };
            u32x4 f1 = { half ? rB0 : pk[4], half ? rB1 : pk[5],
                         half ? pk[6] : rB0, half ? pk[7] : rB1 };
            union { u32x4 u; bf16x8 b; } c0{f0}, c1{f1};
            pf[2 * t + 0] = c0.b;
            pf[2 * t + 1] = c1.b;
        }

        #pragma unroll
        for (int ks = 0; ks < 4; ks++) {
            bf16x8 v0f = *(const bf16x8*)&Vs[buf][(l32)      * 64 + fgo[ks]];
            bf16x8 v1f = *(const bf16x8*)&Vs[buf][(32 + l32) * 64 + fgo[ks]];
            lsum = __builtin_amdgcn_mfma_f32_32x32x16_bf16(pf[ks], ones, lsum, 0, 0, 0);
            o0   = __builtin_amdgcn_mfma_f32_32x32x16_bf16(pf[ks], v0f, o0, 0, 0, 0);
            o1   = __builtin_amdgcn_mfma_f32_32x32x16_bf16(pf[ks], v1f, o1, 0, 0, 0);
        }
    }

    #pragma unroll
    for (int reg = 0; reg < 16; reg++) {
        float inv = 1.0f / lsum[reg];
        int row = (reg & 3) + 8 * (reg >> 2) + 4 * half;
        int qrow = qt * 128 + wave * 32 + row;
        size_t base = (size_t)(b * 1024 + qrow) * 768 + h * 64 + l32;
        ctx[base]      = f2bf(o0[reg] * inv);
        ctx[base + 32] = f2bf(o1[reg] * inv);
    }
}

// ---------------------------------------------------------------------------
extern "C" void kernel_launch(void* const* d_in, const int* in_sizes, int n_in,
                              void* d_out, int out_size, void* d_ws, size_t ws_size,
                              hipStream_t stream) {
    const float* x      = (const float*)d_in[0];  // [8,1024,768]
    const float* w_qkv  = (const float*)d_in[1];  // [768,2304]
    const float* w_proj = (const float*)d_in[2];  // [768,768]
    const float* b_proj = (const float*)d_in[3];  // [768]
    float* out = (float*)d_out;

    const int BN = 8192;     // B*N
    const int C = 768, C3 = 2304;
    const float CE = 0.18033688011112042f;  // 0.125 * log2(e)

    u16* Xb      = (u16*)d_ws;                       // 8192*768
    u16* Wqkv_t  = Xb + (size_t)BN * C;              // 2304*768
    u16* Wproj_t = Wqkv_t + (size_t)C3 * C;          // 768*768
    u16* QKV     = Wproj_t + (size_t)C * C;          // 8192*2304 (Q,K used)
    u16* Vt      = QKV + (size_t)BN * C3;            // 96*64*1024
    u16* Ctx     = Vt + (size_t)96 * 64 * 1024;      // 8192*768

    static bool s_attr = false;
    if (!s_attr) {
        (void)hipFuncSetAttribute((const void*)gemm_qkv<768>,
                                  hipFuncAttributeMaxDynamicSharedMemorySize, 147456);
        s_attr = true;
    }

    convert_bf16<<<(BN * C / 4 + 255) / 256, 256, 0, stream>>>(x, Xb, BN * C / 4);
    prep_weights<<<2304, 256, 0, stream>>>(w_qkv, w_proj, Wqkv_t, Wproj_t);

    gemm_qkv<768><<<576, 512, 147456, stream>>>(Xb, Wqkv_t, QKV, Vt, CE);

    attn_kernel<<<dim3(8, 96), 256, 0, stream>>>(QKV, Vt, Ctx);

    gemm_proj<768><<<dim3(C / 128, BN / 128), 256, 0, stream>>>(
        Ctx, Wproj_t, out, b_proj, BN, C);
}

// Round 7
// 195.069 us; speedup vs baseline: 1.0099x; 1.0099x over previous
//
#include <hip/hip_runtime.h>

typedef __bf16 bf16x8 __attribute__((ext_vector_type(8)));
typedef float f32x4 __attribute__((ext_vector_type(4)));
typedef float f32x16 __attribute__((ext_vector_type(16)));
typedef unsigned short u16;
typedef unsigned int u32;
typedef u16 u16x4 __attribute__((ext_vector_type(4)));
typedef u32 u32x4 __attribute__((ext_vector_type(4)));

__device__ __forceinline__ u16 f2bf(float f) {
    union { float f; u32 u; } x{f};
    u32 r = x.u + 0x7FFFu + ((x.u >> 16) & 1u);  // RNE
    return (u16)(r >> 16);
}

__device__ __forceinline__ float ex2(float x) {
#if __has_builtin(__builtin_amdgcn_exp2f)
    return __builtin_amdgcn_exp2f(x);
#else
    return __expf(x * 0.6931471805599453f);
#endif
}

// round-half-up bf16 (inputs >= 0), packed pair into u32
__device__ __forceinline__ u32 pkbf(float a, float b) {
    union { float f; u32 u; } ca{a}, cb{b};
    return ((ca.u + 0x8000u) >> 16) | (((cb.u + 0x8000u) >> 16) << 16);
}

// async global->LDS, 16B per lane; LDS dest = wave-uniform base + lane*16
#define GLD16(g, l)                                                            \
    __builtin_amdgcn_global_load_lds(                                          \
        (const __attribute__((address_space(1))) u32*)(g),                     \
        (__attribute__((address_space(3))) u32*)(l), 16, 0, 0)

// ---------------------------------------------------------------------------
// R7: convert + both weight transposes MERGED into one dispatch (removes one
// launch boundary; the independent memory streams overlap).
//   blocks 0..6143      : fp32->bf16 convert of x (256 thr x 4 floats)
//   blocks 6144..8447   : 32x32 transpose tiles of w_qkv / w_proj
// ---------------------------------------------------------------------------
__global__ __launch_bounds__(256) void prep_all(
    const float* __restrict__ x,
    const float* __restrict__ wq, const float* __restrict__ wp,
    u16* __restrict__ Xb,
    u16* __restrict__ WqT, u16* __restrict__ WpT)
{
    __shared__ u16 tile[32][33];
    int id = blockIdx.x;
    if (id < 6144) {
        int i = id * 256 + threadIdx.x;          // n4 = 8192*768/4 = 1572864 = 6144*256
        float4 f = *(const float4*)(x + (size_t)i * 4);
        u16x4 u = { f2bf(f.x), f2bf(f.y), f2bf(f.z), f2bf(f.w) };
        *(u16x4*)(Xb + (size_t)i * 4) = u;
        return;
    }
    id -= 6144;
    const float* src; u16* dst; int R, C, bx, by;
    if (id < 1728) { src = wq; dst = WqT; R = 768; C = 2304; bx = (id % 72) * 32; by = (id / 72) * 32; }
    else { id -= 1728; src = wp; dst = WpT; R = 768; C = 768; bx = (id % 24) * 32; by = (id / 24) * 32; }
    int xx = threadIdx.x & 31, yy = threadIdx.x >> 5;
    #pragma unroll
    for (int i = 0; i < 32; i += 8)
        tile[yy + i][xx] = f2bf(src[(size_t)(by + yy + i) * C + bx + xx]);
    __syncthreads();
    #pragma unroll
    for (int i = 0; i < 32; i += 8)
        dst[(size_t)(bx + yy + i) * R + by + xx] = tile[xx][yy + i];
}

// ---------------------------------------------------------------------------
// QKV GEMM (unchanged from R6, best-measured variant): 256x128 tile, 512
// threads / 8 waves (4M x 2N, per-wave 64x64), 16x16x32 MFMA with the
// measured conflict-free XOR-granule pattern, 3-buffer LDS (144 KiB),
// stage-ahead-2, counted s_waitcnt vmcnt(6), 2-phase fine interleave.
// Grid 576 = 32 row-tiles x 18 col-tiles, XCD-chunked bijectively (8*72).
// V-section (bn>=1536) swaps MFMA operands -> Vt scatter.
// ---------------------------------------------------------------------------
#define MFMA16 __builtin_amdgcn_mfma_f32_16x16x32_bf16

#define STG_P0(tt)                                                              \
    {                                                                           \
        u16* ab_ = &lds[((tt) % 3) * 24576];                                    \
        GLD16(Ap + (tt) * 64 + (size_t)0 * 8 * K, &ab_[(wave * 32 + 0)  * 64]); \
        GLD16(Ap + (tt) * 64 + (size_t)1 * 8 * K, &ab_[(wave * 32 + 8)  * 64]); \
        GLD16(Ap + (tt) * 64 + (size_t)2 * 8 * K, &ab_[(wave * 32 + 16) * 64]); \
    }
#define STG_P1(tt)                                                              \
    {                                                                           \
        u16* ab_ = &lds[((tt) % 3) * 24576];                                    \
        GLD16(Ap + (tt) * 64 + (size_t)3 * 8 * K, &ab_[(wave * 32 + 24) * 64]); \
        GLD16(Bp + (tt) * 64 + (size_t)0 * 8 * K, &ab_[16384 + (wave * 16 + 0) * 64]); \
        GLD16(Bp + (tt) * 64 + (size_t)1 * 8 * K, &ab_[16384 + (wave * 16 + 8) * 64]); \
    }

template <int K>
__global__ __launch_bounds__(512, 1) void gemm_qkv(
    const u16* __restrict__ A,
    const u16* __restrict__ Wt,
    u16* __restrict__ QKV,
    u16* __restrict__ Vt,
    float qscale)
{
    extern __shared__ __align__(16) u16 lds[];   // 3 * (256*64 + 128*64) u16 = 144 KiB

    constexpr int NT = K / 64;   // 12 K-tiles

    int tid = threadIdx.x;
    int wave = tid >> 6, lane = tid & 63;
    int quad = lane >> 4, l16 = lane & 15;
    int wm = (wave >> 1) * 64;      // 4 M-waves: 0,64,128,192
    int wn = (wave & 1) * 64;       // 2 N-waves: 0,64

    int id = blockIdx.x;
    int lin = (id & 7) * 72 + (id >> 3);    // XCD-chunked, bijective (576 = 8*72)
    int bm = (lin / 18) * 256;              // 32 row-tiles
    int bn = (lin % 18) * 128;              // 18 col-tiles
    bool vsec = (bn >= 1536);

    f32x4 acc[4][4] = {};

    int srow = lane >> 3;
    int scg = ((lane & 7) ^ srow) * 8;
    const u16* Ap = A  + (size_t)(bm + wave * 32 + srow) * K + scg;
    const u16* Bp = Wt + (size_t)(bn + wave * 16 + srow) * K + scg;

    int fg0 = ((0 * 4 + quad) ^ (l16 & 7)) * 8;
    int fg1 = ((1 * 4 + quad) ^ (l16 & 7)) * 8;

    // prologue: stage tiles 0,1 (12 loads/thread); wait tile 0 (6 in flight)
    STG_P0(0); STG_P1(0);
    STG_P0(1); STG_P1(1);
    asm volatile("s_waitcnt vmcnt(6)" ::: "memory");
    __builtin_amdgcn_s_barrier();

    #pragma unroll 3
    for (int t = 0; t < NT; ++t) {
        const u16* Ab = &lds[(t % 3) * 24576];
        const u16* Bb = Ab + 16384;

        // ---- phase 0 (k-half 0): 8 ds_reads + 3 staging -> bar -> 16 MFMA -> bar
        {
            bf16x8 af[4], bfr[4];
            #pragma unroll
            for (int i = 0; i < 4; i++) {
                af[i]  = *(const bf16x8*)&Ab[(wm + i * 16 + l16) * 64 + fg0];
                bfr[i] = *(const bf16x8*)&Bb[(wn + i * 16 + l16) * 64 + fg0];
            }
            if (t + 2 < NT) STG_P0(t + 2);
            __builtin_amdgcn_s_barrier();
            __builtin_amdgcn_s_setprio(1);
            if (!vsec) {
                #pragma unroll
                for (int mi = 0; mi < 4; mi++)
                    #pragma unroll
                    for (int ni = 0; ni < 4; ni++)
                        acc[mi][ni] = MFMA16(af[mi], bfr[ni], acc[mi][ni], 0, 0, 0);
            } else {
                #pragma unroll
                for (int mi = 0; mi < 4; mi++)
                    #pragma unroll
                    for (int ni = 0; ni < 4; ni++)
                        acc[mi][ni] = MFMA16(bfr[ni], af[mi], acc[mi][ni], 0, 0, 0);
            }
            __builtin_amdgcn_s_setprio(0);
            __builtin_amdgcn_s_barrier();
        }

        // ---- phase 1 (k-half 1): 8 ds_reads + 3 staging -> bar -> 16 MFMA -> boundary
        {
            bf16x8 af[4], bfr[4];
            #pragma unroll
            for (int i = 0; i < 4; i++) {
                af[i]  = *(const bf16x8*)&Ab[(wm + i * 16 + l16) * 64 + fg1];
                bfr[i] = *(const bf16x8*)&Bb[(wn + i * 16 + l16) * 64 + fg1];
            }
            if (t + 2 < NT) STG_P1(t + 2);
            __builtin_amdgcn_s_barrier();
            __builtin_amdgcn_s_setprio(1);
            if (!vsec) {
                #pragma unroll
                for (int mi = 0; mi < 4; mi++)
                    #pragma unroll
                    for (int ni = 0; ni < 4; ni++)
                        acc[mi][ni] = MFMA16(af[mi], bfr[ni], acc[mi][ni], 0, 0, 0);
            } else {
                #pragma unroll
                for (int mi = 0; mi < 4; mi++)
                    #pragma unroll
                    for (int ni = 0; ni < 4; ni++)
                        acc[mi][ni] = MFMA16(bfr[ni], af[mi], acc[mi][ni], 0, 0, 0);
            }
            __builtin_amdgcn_s_setprio(0);
            // boundary: t+1's 6 loads must be done; t+2's 6 stay in flight
            if (t + 1 < NT) {
                if (t + 2 < NT) { asm volatile("s_waitcnt vmcnt(6)" ::: "memory"); }
                else            { asm volatile("s_waitcnt vmcnt(0)" ::: "memory"); }
            }
            __builtin_amdgcn_s_barrier();
        }
    }

    if (!vsec) {
        float sc = (bn < 768) ? qscale : 1.0f;   // col-tile is uniformly Q or K
        #pragma unroll
        for (int mi = 0; mi < 4; mi++) {
            #pragma unroll
            for (int ni = 0; ni < 4; ni++) {
                #pragma unroll
                for (int rg = 0; rg < 4; rg++) {
                    int row = bm + wm + mi * 16 + quad * 4 + rg;
                    int col = bn + wn + ni * 16 + l16;
                    QKV[(size_t)row * 2304 + col] = f2bf(acc[mi][ni][rg] * sc);
                }
            }
        }
    } else {
        #pragma unroll
        for (int mi = 0; mi < 4; mi++) {
            #pragma unroll
            for (int ni = 0; ni < 4; ni++) {
                #pragma unroll
                for (int rg = 0; rg < 4; rg++) {
                    int d = (bn - 1536) + wn + ni * 16 + quad * 4 + rg;
                    int ng = bm + wm + mi * 16 + l16;
                    int b = ng >> 10, n = ng & 1023, h = d >> 6;
                    Vt[((size_t)(b * 12 + h) * 64 + (d & 63)) * 1024 + n] = f2bf(acc[mi][ni][rg]);
                }
            }
        }
    }
}

#undef STG_P0
#undef STG_P1

// ---------------------------------------------------------------------------
// Output projection GEMM: R0-proven single-buffer 16x16 form (zero-conflict).
// ---------------------------------------------------------------------------
template <int K>
__global__ __launch_bounds__(256) void gemm_proj(
    const u16* __restrict__ A,
    const u16* __restrict__ Bt,
    float* __restrict__ Cp,
    const float* __restrict__ bias,
    int M, int N)
{
    __shared__ __align__(16) u16 As[128 * 64];
    __shared__ __align__(16) u16 Bs[128 * 64];

    int tid = threadIdx.x;
    int wave = tid >> 6, lane = tid & 63;
    int quad = lane >> 4, l16 = lane & 15;
    int wm = (wave >> 1) * 64, wn = (wave & 1) * 64;
    int bm = blockIdx.y * 128, bn = blockIdx.x * 128;

    f32x4 acc[4][4] = {};

    int srow = lane >> 3;
    int scg = ((lane & 7) ^ srow) * 8;
    const u16* Ap = A + (size_t)(bm + wave * 32 + srow) * K + scg;
    const u16* Bp = Bt + (size_t)(bn + wave * 32 + srow) * K + scg;

    int fg0 = (((0 * 4 + quad) ^ (l16 & 7)) * 8);
    int fg1 = (((1 * 4 + quad) ^ (l16 & 7)) * 8);

    for (int k0 = 0; k0 < K; k0 += 64) {
        #pragma unroll
        for (int j = 0; j < 4; j++) {
            GLD16(Ap + k0 + (size_t)j * 8 * K, &As[(wave * 32 + j * 8) * 64]);
            GLD16(Bp + k0 + (size_t)j * 8 * K, &Bs[(wave * 32 + j * 8) * 64]);
        }
        __syncthreads();

        #pragma unroll
        for (int h = 0; h < 2; h++) {
            int fg = h ? fg1 : fg0;
            bf16x8 af[4], bfr[4];
            #pragma unroll
            for (int i = 0; i < 4; i++) {
                af[i]  = *(const bf16x8*)&As[(wm + i * 16 + l16) * 64 + fg];
                bfr[i] = *(const bf16x8*)&Bs[(wn + i * 16 + l16) * 64 + fg];
            }
            #pragma unroll
            for (int mi = 0; mi < 4; mi++)
                #pragma unroll
                for (int ni = 0; ni < 4; ni++)
                    acc[mi][ni] = __builtin_amdgcn_mfma_f32_16x16x32_bf16(af[mi], bfr[ni], acc[mi][ni], 0, 0, 0);
        }
        __syncthreads();
    }

    #pragma unroll
    for (int mi = 0; mi < 4; mi++) {
        #pragma unroll
        for (int ni = 0; ni < 4; ni++) {
            #pragma unroll
            for (int rg = 0; rg < 4; rg++) {
                int row = bm + wm + mi * 16 + quad * 4 + rg;
                int col = bn + wn + ni * 16 + l16;
                Cp[(size_t)row * N + col] = acc[mi][ni][rg] + bias[col];
            }
        }
    }
}

// ---------------------------------------------------------------------------
// Flash attention v4, R7: + s_setprio(1/0) around the QK^T and PV MFMA
// clusters (T5; measured +4-7% on attn in the independent-block regime).
// Everything else unchanged.
// ---------------------------------------------------------------------------
__global__ __launch_bounds__(256, 4) void attn_kernel(
    const u16* __restrict__ qkv,
    const u16* __restrict__ Vt,
    u16* __restrict__ ctx)
{
    __shared__ __align__(16) u16 Ks[2][4096];   // 2 x 64key x 64d (swizzled)
    __shared__ __align__(16) u16 Vs[2][4096];   // 2 x 64d x 64key (swizzled)

    int qt = blockIdx.x;            // 0..7 (128 q rows per block)
    int bh = blockIdx.y;            // 0..95
    int b = bh / 12, h = bh % 12;
    int tid = threadIdx.x;
    int wave = tid >> 6, lane = tid & 63;
    int l32 = lane & 31, half = lane >> 5;

    const u16* qbase = qkv + (size_t)(b * 1024 + qt * 128 + wave * 32 + l32) * 2304 + h * 64;
    bf16x8 qa[4];
    #pragma unroll
    for (int ks = 0; ks < 4; ks++)
        qa[ks] = *(const bf16x8*)(qbase + ks * 16 + half * 8);

    int srow = lane >> 3;
    int scol = (lane & 7) ^ srow;
    const u16* kA = qkv + (size_t)(b * 1024 + wave * 16 + srow) * 2304 + 768 + h * 64 + scol * 8;
    const u16* vA = Vt + ((size_t)bh * 64 + wave * 16 + srow) * 1024 + scol * 8;

    bf16x8 ones;
    #pragma unroll
    for (int j = 0; j < 8; j++) ((u16*)&ones)[j] = 0x3F80;  // bf16 1.0

    f32x16 o0 = {}, o1 = {}, lsum = {};

    int fgo[4];
    #pragma unroll
    for (int ks = 0; ks < 4; ks++)
        fgo[ks] = (((ks * 2 + half) ^ (lane & 7)) * 8);

    {
        GLD16(kA,            &Ks[0][(wave * 2 + 0) * 512]);
        GLD16(kA + 8 * 2304, &Ks[0][(wave * 2 + 1) * 512]);
        GLD16(vA,            &Vs[0][(wave * 2 + 0) * 512]);
        GLD16(vA + 8 * 1024, &Vs[0][(wave * 2 + 1) * 512]);
    }

    #pragma unroll 2
    for (int kt = 0; kt < 16; kt++) {
        int buf = kt & 1;
        __syncthreads();   // drains vmcnt(0): buf is populated

        if (kt < 15) {
            const u16* k0 = kA + (size_t)(kt + 1) * (64 * 2304);
            const u16* v0 = vA + (size_t)(kt + 1) * 64;
            GLD16(k0,            &Ks[buf ^ 1][(wave * 2 + 0) * 512]);
            GLD16(k0 + 8 * 2304, &Ks[buf ^ 1][(wave * 2 + 1) * 512]);
            GLD16(v0,            &Vs[buf ^ 1][(wave * 2 + 0) * 512]);
            GLD16(v0 + 8 * 1024, &Vs[buf ^ 1][(wave * 2 + 1) * 512]);
        }

        f32x16 st0 = {}, st1 = {};
        __builtin_amdgcn_s_setprio(1);
        #pragma unroll
        for (int ks = 0; ks < 4; ks++) {
            bf16x8 kf0 = *(const bf16x8*)&Ks[buf][(l32)      * 64 + fgo[ks]];
            bf16x8 kf1 = *(const bf16x8*)&Ks[buf][(32 + l32) * 64 + fgo[ks]];
            st0 = __builtin_amdgcn_mfma_f32_32x32x16_bf16(kf0, qa[ks], st0, 0, 0, 0);
            st1 = __builtin_amdgcn_mfma_f32_32x32x16_bf16(kf1, qa[ks], st1, 0, 0, 0);
        }
        __builtin_amdgcn_s_setprio(0);

        bf16x8 pf[4];
        #pragma unroll
        for (int t = 0; t < 2; t++) {
            u32 pk[8];
            #pragma unroll
            for (int g = 0; g < 4; g++) {
                float p0 = ex2(t ? st1[4 * g + 0] : st0[4 * g + 0]);
                float p1 = ex2(t ? st1[4 * g + 1] : st0[4 * g + 1]);
                float p2 = ex2(t ? st1[4 * g + 2] : st0[4 * g + 2]);
                float p3 = ex2(t ? st1[4 * g + 3] : st0[4 * g + 3]);
                pk[2 * g + 0] = pkbf(p0, p1);
                pk[2 * g + 1] = pkbf(p2, p3);
            }
            u32 rA0 = __shfl_xor(half ? pk[0] : pk[2], 32);
            u32 rA1 = __shfl_xor(half ? pk[1] : pk[3], 32);
            u32 rB0 = __shfl_xor(half ? pk[4] : pk[6], 32);
            u32 rB1 = __shfl_xor(half ? pk[5] : pk[7], 32);
            u32x4 f0 = { half ? rA0 : pk[0], half ? rA1 : pk[1],
                         half ? pk[2] : rA0, half ? pk[3] : rA1 };
            u32x4 f1 = { half ? rB0 : pk[4], half ? rB1 : pk[5],
                         half ? pk[6] : rB0, half ? pk[7] : rB1 };
            union { u32x4 u; bf16x8 b; } c0{f0}, c1{f1};
            pf[2 * t + 0] = c0.b;
            pf[2 * t + 1] = c1.b;
        }

        __builtin_amdgcn_s_setprio(1);
        #pragma unroll
        for (int ks = 0; ks < 4; ks++) {
            bf16x8 v0f = *(const bf16x8*)&Vs[buf][(l32)      * 64 + fgo[ks]];
            bf16x8 v1f = *(const bf16x8*)&Vs[buf][(32 + l32) * 64 + fgo[ks]];
            lsum = __builtin_amdgcn_mfma_f32_32x32x16_bf16(pf[ks], ones, lsum, 0, 0, 0);
            o0   = __builtin_amdgcn_mfma_f32_32x32x16_bf16(pf[ks], v0f, o0, 0, 0, 0);
            o1   = __builtin_amdgcn_mfma_f32_32x32x16_bf16(pf[ks], v1f, o1, 0, 0, 0);
        }
        __builtin_amdgcn_s_setprio(0);
    }

    #pragma unroll
    for (int reg = 0; reg < 16; reg++) {
        float inv = 1.0f / lsum[reg];
        int row = (reg & 3) + 8 * (reg >> 2) + 4 * half;
        int qrow = qt * 128 + wave * 32 + row;
        size_t base = (size_t)(b * 1024 + qrow) * 768 + h * 64 + l32;
        ctx[base]      = f2bf(o0[reg] * inv);
        ctx[base + 32] = f2bf(o1[reg] * inv);
    }
}

// ---------------------------------------------------------------------------
extern "C" void kernel_launch(void* const* d_in, const int* in_sizes, int n_in,
                              void* d_out, int out_size, void* d_ws, size_t ws_size,
                              hipStream_t stream) {
    const float* x      = (const float*)d_in[0];  // [8,1024,768]
    const float* w_qkv  = (const float*)d_in[1];  // [768,2304]
    const float* w_proj = (const float*)d_in[2];  // [768,768]
    const float* b_proj = (const float*)d_in[3];  // [768]
    float* out = (float*)d_out;

    const int BN = 8192;     // B*N
    const int C = 768, C3 = 2304;
    const float CE = 0.18033688011112042f;  // 0.125 * log2(e)

    u16* Xb      = (u16*)d_ws;                       // 8192*768
    u16* Wqkv_t  = Xb + (size_t)BN * C;              // 2304*768
    u16* Wproj_t = Wqkv_t + (size_t)C3 * C;          // 768*768
    u16* QKV     = Wproj_t + (size_t)C * C;          // 8192*2304 (Q,K used)
    u16* Vt      = QKV + (size_t)BN * C3;            // 96*64*1024
    u16* Ctx     = Vt + (size_t)96 * 64 * 1024;      // 8192*768

    static bool s_attr = false;
    if (!s_attr) {
        (void)hipFuncSetAttribute((const void*)gemm_qkv<768>,
                                  hipFuncAttributeMaxDynamicSharedMemorySize, 147456);
        s_attr = true;
    }

    prep_all<<<8448, 256, 0, stream>>>(x, w_qkv, w_proj, Xb, Wqkv_t, Wproj_t);

    gemm_qkv<768><<<576, 512, 147456, stream>>>(Xb, Wqkv_t, QKV, Vt, CE);

    attn_kernel<<<dim3(8, 96), 256, 0, stream>>>(QKV, Vt, Ctx);

    gemm_proj<768><<<dim3(C / 128, BN / 128), 256, 0, stream>>>(
        Ctx, Wproj_t, out, b_proj, BN, C);
}

// Round 8
// 189.650 us; speedup vs baseline: 1.0388x; 1.0286x over previous
//
#include <hip/hip_runtime.h>

typedef __bf16 bf16x8 __attribute__((ext_vector_type(8)));
typedef float f32x4 __attribute__((ext_vector_type(4)));
typedef float f32x16 __attribute__((ext_vector_type(16)));
typedef unsigned short u16;
typedef unsigned int u32;
typedef u16 u16x4 __attribute__((ext_vector_type(4)));
typedef u32 u32x4 __attribute__((ext_vector_type(4)));

__device__ __forceinline__ u16 f2bf(float f) {
    union { float f; u32 u; } x{f};
    u32 r = x.u + 0x7FFFu + ((x.u >> 16) & 1u);  // RNE
    return (u16)(r >> 16);
}

__device__ __forceinline__ float ex2(float x) {
#if __has_builtin(__builtin_amdgcn_exp2f)
    return __builtin_amdgcn_exp2f(x);
#else
    return __expf(x * 0.6931471805599453f);
#endif
}

// packed f32 pair -> bf16x2 in one VALU op (RNE). Our hand-rolled bit-math
// (5 ops) is not fusable by the compiler; this is T12's primitive.
__device__ __forceinline__ u32 cvtpk(float a, float b) {
    u32 r;
    asm("v_cvt_pk_bf16_f32 %0, %1, %2" : "=v"(r) : "v"(a), "v"(b));
    return r;
}

// async global->LDS, 16B per lane; LDS dest = wave-uniform base + lane*16
#define GLD16(g, l)                                                            \
    __builtin_amdgcn_global_load_lds(                                          \
        (const __attribute__((address_space(1))) u32*)(g),                     \
        (__attribute__((address_space(3))) u32*)(l), 16, 0, 0)

// ---------------------------------------------------------------------------
// Merged prep: fp32->bf16 convert of x + both weight transposes.
// ---------------------------------------------------------------------------
__global__ __launch_bounds__(256) void prep_all(
    const float* __restrict__ x,
    const float* __restrict__ wq, const float* __restrict__ wp,
    u16* __restrict__ Xb,
    u16* __restrict__ WqT, u16* __restrict__ WpT)
{
    __shared__ u16 tile[32][33];
    int id = blockIdx.x;
    if (id < 6144) {
        int i = id * 256 + threadIdx.x;          // n4 = 8192*768/4 = 1572864 = 6144*256
        float4 f = *(const float4*)(x + (size_t)i * 4);
        u16x4 u = { f2bf(f.x), f2bf(f.y), f2bf(f.z), f2bf(f.w) };
        *(u16x4*)(Xb + (size_t)i * 4) = u;
        return;
    }
    id -= 6144;
    const float* src; u16* dst; int R, C, bx, by;
    if (id < 1728) { src = wq; dst = WqT; R = 768; C = 2304; bx = (id % 72) * 32; by = (id / 72) * 32; }
    else { id -= 1728; src = wp; dst = WpT; R = 768; C = 768; bx = (id % 24) * 32; by = (id / 24) * 32; }
    int xx = threadIdx.x & 31, yy = threadIdx.x >> 5;
    #pragma unroll
    for (int i = 0; i < 32; i += 8)
        tile[yy + i][xx] = f2bf(src[(size_t)(by + yy + i) * C + bx + xx]);
    __syncthreads();
    #pragma unroll
    for (int i = 0; i < 32; i += 8)
        dst[(size_t)(bx + yy + i) * R + by + xx] = tile[xx][yy + i];
}

// ---------------------------------------------------------------------------
// QKV GEMM, R8: R6 geometry (256x128 tile, 512 thr / 8 waves of 64x64,
// 16x16x32 MFMA, conflict-free XOR-granule pattern, 3-buffer 144 KiB LDS,
// stage-ahead-2, counted vmcnt(6)) but with ONE barrier per K-tile
// (R5's best-projected schedule, now without the 32x32 bank conflicts).
// Hazards: intra-tile phases only READ buf[t]; STG targets buf[(t+2)%3] =
// buf[(t-1)%3], which all waves finished reading before the t-1 boundary
// barrier; per-wave vmcnt(6) before the boundary barrier carries staging
// completeness for tile t+1 across all waves.
// Grid 576 = 32 row-tiles x 18 col-tiles, XCD-chunked bijectively (8*72).
// V-section (bn>=1536) swaps MFMA operands -> Vt scatter.
// ---------------------------------------------------------------------------
#define MFMA16 __builtin_amdgcn_mfma_f32_16x16x32_bf16

#define STG_P0(tt)                                                              \
    {                                                                           \
        u16* ab_ = &lds[((tt) % 3) * 24576];                                    \
        GLD16(Ap + (tt) * 64 + (size_t)0 * 8 * K, &ab_[(wave * 32 + 0)  * 64]); \
        GLD16(Ap + (tt) * 64 + (size_t)1 * 8 * K, &ab_[(wave * 32 + 8)  * 64]); \
        GLD16(Ap + (tt) * 64 + (size_t)2 * 8 * K, &ab_[(wave * 32 + 16) * 64]); \
    }
#define STG_P1(tt)                                                              \
    {                                                                           \
        u16* ab_ = &lds[((tt) % 3) * 24576];                                    \
        GLD16(Ap + (tt) * 64 + (size_t)3 * 8 * K, &ab_[(wave * 32 + 24) * 64]); \
        GLD16(Bp + (tt) * 64 + (size_t)0 * 8 * K, &ab_[16384 + (wave * 16 + 0) * 64]); \
        GLD16(Bp + (tt) * 64 + (size_t)1 * 8 * K, &ab_[16384 + (wave * 16 + 8) * 64]); \
    }

template <int K>
__global__ __launch_bounds__(512, 1) void gemm_qkv(
    const u16* __restrict__ A,
    const u16* __restrict__ Wt,
    u16* __restrict__ QKV,
    u16* __restrict__ Vt,
    float qscale)
{
    extern __shared__ __align__(16) u16 lds[];   // 3 * (256*64 + 128*64) u16 = 144 KiB

    constexpr int NT = K / 64;   // 12 K-tiles

    int tid = threadIdx.x;
    int wave = tid >> 6, lane = tid & 63;
    int quad = lane >> 4, l16 = lane & 15;
    int wm = (wave >> 1) * 64;      // 4 M-waves: 0,64,128,192
    int wn = (wave & 1) * 64;       // 2 N-waves: 0,64

    int id = blockIdx.x;
    int lin = (id & 7) * 72 + (id >> 3);    // XCD-chunked, bijective (576 = 8*72)
    int bm = (lin / 18) * 256;              // 32 row-tiles
    int bn = (lin % 18) * 128;              // 18 col-tiles
    bool vsec = (bn >= 1536);

    f32x4 acc[4][4] = {};

    int srow = lane >> 3;
    int scg = ((lane & 7) ^ srow) * 8;
    const u16* Ap = A  + (size_t)(bm + wave * 32 + srow) * K + scg;
    const u16* Bp = Wt + (size_t)(bn + wave * 16 + srow) * K + scg;

    int fg0 = ((0 * 4 + quad) ^ (l16 & 7)) * 8;
    int fg1 = ((1 * 4 + quad) ^ (l16 & 7)) * 8;

    // prologue: stage tiles 0,1 (12 loads/thread); wait tile 0 (6 in flight)
    STG_P0(0); STG_P1(0);
    STG_P0(1); STG_P1(1);
    asm volatile("s_waitcnt vmcnt(6)" ::: "memory");
    __builtin_amdgcn_s_barrier();

    #pragma unroll 3
    for (int t = 0; t < NT; ++t) {
        const u16* Ab = &lds[(t % 3) * 24576];
        const u16* Bb = Ab + 16384;

        // ---- k-half 0: 8 ds_reads + 3 staging -> 16 MFMA (no barrier) ----
        {
            bf16x8 af[4], bfr[4];
            #pragma unroll
            for (int i = 0; i < 4; i++) {
                af[i]  = *(const bf16x8*)&Ab[(wm + i * 16 + l16) * 64 + fg0];
                bfr[i] = *(const bf16x8*)&Bb[(wn + i * 16 + l16) * 64 + fg0];
            }
            if (t + 2 < NT) STG_P0(t + 2);
            __builtin_amdgcn_s_setprio(1);
            if (!vsec) {
                #pragma unroll
                for (int mi = 0; mi < 4; mi++)
                    #pragma unroll
                    for (int ni = 0; ni < 4; ni++)
                        acc[mi][ni] = MFMA16(af[mi], bfr[ni], acc[mi][ni], 0, 0, 0);
            } else {
                #pragma unroll
                for (int mi = 0; mi < 4; mi++)
                    #pragma unroll
                    for (int ni = 0; ni < 4; ni++)
                        acc[mi][ni] = MFMA16(bfr[ni], af[mi], acc[mi][ni], 0, 0, 0);
            }
            __builtin_amdgcn_s_setprio(0);
        }

        // ---- k-half 1: 8 ds_reads + 3 staging -> 16 MFMA -> boundary ----
        {
            bf16x8 af[4], bfr[4];
            #pragma unroll
            for (int i = 0; i < 4; i++) {
                af[i]  = *(const bf16x8*)&Ab[(wm + i * 16 + l16) * 64 + fg1];
                bfr[i] = *(const bf16x8*)&Bb[(wn + i * 16 + l16) * 64 + fg1];
            }
            if (t + 2 < NT) STG_P1(t + 2);
            __builtin_amdgcn_s_setprio(1);
            if (!vsec) {
                #pragma unroll
                for (int mi = 0; mi < 4; mi++)
                    #pragma unroll
                    for (int ni = 0; ni < 4; ni++)
                        acc[mi][ni] = MFMA16(af[mi], bfr[ni], acc[mi][ni], 0, 0, 0);
            } else {
                #pragma unroll
                for (int mi = 0; mi < 4; mi++)
                    #pragma unroll
                    for (int ni = 0; ni < 4; ni++)
                        acc[mi][ni] = MFMA16(bfr[ni], af[mi], acc[mi][ni], 0, 0, 0);
            }
            __builtin_amdgcn_s_setprio(0);
            // boundary: t+1's 6 loads must be done; t+2's 6 stay in flight
            if (t + 1 < NT) {
                if (t + 2 < NT) { asm volatile("s_waitcnt vmcnt(6)" ::: "memory"); }
                else            { asm volatile("s_waitcnt vmcnt(0)" ::: "memory"); }
                __builtin_amdgcn_s_barrier();
            }
        }
    }

    if (!vsec) {
        float sc = (bn < 768) ? qscale : 1.0f;   // col-tile is uniformly Q or K
        #pragma unroll
        for (int mi = 0; mi < 4; mi++) {
            #pragma unroll
            for (int ni = 0; ni < 4; ni++) {
                #pragma unroll
                for (int rg = 0; rg < 4; rg++) {
                    int row = bm + wm + mi * 16 + quad * 4 + rg;
                    int col = bn + wn + ni * 16 + l16;
                    QKV[(size_t)row * 2304 + col] = f2bf(acc[mi][ni][rg] * sc);
                }
            }
        }
    } else {
        #pragma unroll
        for (int mi = 0; mi < 4; mi++) {
            #pragma unroll
            for (int ni = 0; ni < 4; ni++) {
                #pragma unroll
                for (int rg = 0; rg < 4; rg++) {
                    int d = (bn - 1536) + wn + ni * 16 + quad * 4 + rg;
                    int ng = bm + wm + mi * 16 + l16;
                    int b = ng >> 10, n = ng & 1023, h = d >> 6;
                    Vt[((size_t)(b * 12 + h) * 64 + (d & 63)) * 1024 + n] = f2bf(acc[mi][ni][rg]);
                }
            }
        }
    }
}

#undef STG_P0
#undef STG_P1

// ---------------------------------------------------------------------------
// Output projection GEMM: R0-proven single-buffer 16x16 form (zero-conflict).
// ---------------------------------------------------------------------------
template <int K>
__global__ __launch_bounds__(256) void gemm_proj(
    const u16* __restrict__ A,
    const u16* __restrict__ Bt,
    float* __restrict__ Cp,
    const float* __restrict__ bias,
    int M, int N)
{
    __shared__ __align__(16) u16 As[128 * 64];
    __shared__ __align__(16) u16 Bs[128 * 64];

    int tid = threadIdx.x;
    int wave = tid >> 6, lane = tid & 63;
    int quad = lane >> 4, l16 = lane & 15;
    int wm = (wave >> 1) * 64, wn = (wave & 1) * 64;
    int bm = blockIdx.y * 128, bn = blockIdx.x * 128;

    f32x4 acc[4][4] = {};

    int srow = lane >> 3;
    int scg = ((lane & 7) ^ srow) * 8;
    const u16* Ap = A + (size_t)(bm + wave * 32 + srow) * K + scg;
    const u16* Bp = Bt + (size_t)(bn + wave * 32 + srow) * K + scg;

    int fg0 = (((0 * 4 + quad) ^ (l16 & 7)) * 8);
    int fg1 = (((1 * 4 + quad) ^ (l16 & 7)) * 8);

    for (int k0 = 0; k0 < K; k0 += 64) {
        #pragma unroll
        for (int j = 0; j < 4; j++) {
            GLD16(Ap + k0 + (size_t)j * 8 * K, &As[(wave * 32 + j * 8) * 64]);
            GLD16(Bp + k0 + (size_t)j * 8 * K, &Bs[(wave * 32 + j * 8) * 64]);
        }
        __syncthreads();

        #pragma unroll
        for (int h = 0; h < 2; h++) {
            int fg = h ? fg1 : fg0;
            bf16x8 af[4], bfr[4];
            #pragma unroll
            for (int i = 0; i < 4; i++) {
                af[i]  = *(const bf16x8*)&As[(wm + i * 16 + l16) * 64 + fg];
                bfr[i] = *(const bf16x8*)&Bs[(wn + i * 16 + l16) * 64 + fg];
            }
            #pragma unroll
            for (int mi = 0; mi < 4; mi++)
                #pragma unroll
                for (int ni = 0; ni < 4; ni++)
                    acc[mi][ni] = __builtin_amdgcn_mfma_f32_16x16x32_bf16(af[mi], bfr[ni], acc[mi][ni], 0, 0, 0);
        }
        __syncthreads();
    }

    #pragma unroll
    for (int mi = 0; mi < 4; mi++) {
        #pragma unroll
        for (int ni = 0; ni < 4; ni++) {
            #pragma unroll
            for (int rg = 0; rg < 4; rg++) {
                int row = bm + wm + mi * 16 + quad * 4 + rg;
                int col = bn + wn + ni * 16 + l16;
                Cp[(size_t)row * N + col] = acc[mi][ni][rg] + bias[col];
            }
        }
    }
}

// ---------------------------------------------------------------------------
// Flash attention v4, R8: __launch_bounds__(256,3) (grid is exactly 3
// blocks/CU -- the old (256,4) capped VGPR at 128 for a 4th block that never
// exists) + v_cvt_pk_bf16_f32 for P packing (1 op vs 5 per pair).
// ---------------------------------------------------------------------------
__global__ __launch_bounds__(256, 3) void attn_kernel(
    const u16* __restrict__ qkv,
    const u16* __restrict__ Vt,
    u16* __restrict__ ctx)
{
    __shared__ __align__(16) u16 Ks[2][4096];   // 2 x 64key x 64d (swizzled)
    __shared__ __align__(16) u16 Vs[2][4096];   // 2 x 64d x 64key (swizzled)

    int qt = blockIdx.x;            // 0..7 (128 q rows per block)
    int bh = blockIdx.y;            // 0..95
    int b = bh / 12, h = bh % 12;
    int tid = threadIdx.x;
    int wave = tid >> 6, lane = tid & 63;
    int l32 = lane & 31, half = lane >> 5;

    const u16* qbase = qkv + (size_t)(b * 1024 + qt * 128 + wave * 32 + l32) * 2304 + h * 64;
    bf16x8 qa[4];
    #pragma unroll
    for (int ks = 0; ks < 4; ks++)
        qa[ks] = *(const bf16x8*)(qbase + ks * 16 + half * 8);

    int srow = lane >> 3;
    int scol = (lane & 7) ^ srow;
    const u16* kA = qkv + (size_t)(b * 1024 + wave * 16 + srow) * 2304 + 768 + h * 64 + scol * 8;
    const u16* vA = Vt + ((size_t)bh * 64 + wave * 16 + srow) * 1024 + scol * 8;

    bf16x8 ones;
    #pragma unroll
    for (int j = 0; j < 8; j++) ((u16*)&ones)[j] = 0x3F80;  // bf16 1.0

    f32x16 o0 = {}, o1 = {}, lsum = {};

    int fgo[4];
    #pragma unroll
    for (int ks = 0; ks < 4; ks++)
        fgo[ks] = (((ks * 2 + half) ^ (lane & 7)) * 8);

    {
        GLD16(kA,            &Ks[0][(wave * 2 + 0) * 512]);
        GLD16(kA + 8 * 2304, &Ks[0][(wave * 2 + 1) * 512]);
        GLD16(vA,            &Vs[0][(wave * 2 + 0) * 512]);
        GLD16(vA + 8 * 1024, &Vs[0][(wave * 2 + 1) * 512]);
    }

    #pragma unroll 2
    for (int kt = 0; kt < 16; kt++) {
        int buf = kt & 1;
        __syncthreads();   // drains vmcnt(0): buf is populated

        if (kt < 15) {
            const u16* k0 = kA + (size_t)(kt + 1) * (64 * 2304);
            const u16* v0 = vA + (size_t)(kt + 1) * 64;
            GLD16(k0,            &Ks[buf ^ 1][(wave * 2 + 0) * 512]);
            GLD16(k0 + 8 * 2304, &Ks[buf ^ 1][(wave * 2 + 1) * 512]);
            GLD16(v0,            &Vs[buf ^ 1][(wave * 2 + 0) * 512]);
            GLD16(v0 + 8 * 1024, &Vs[buf ^ 1][(wave * 2 + 1) * 512]);
        }

        f32x16 st0 = {}, st1 = {};
        __builtin_amdgcn_s_setprio(1);
        #pragma unroll
        for (int ks = 0; ks < 4; ks++) {
            bf16x8 kf0 = *(const bf16x8*)&Ks[buf][(l32)      * 64 + fgo[ks]];
            bf16x8 kf1 = *(const bf16x8*)&Ks[buf][(32 + l32) * 64 + fgo[ks]];
            st0 = __builtin_amdgcn_mfma_f32_32x32x16_bf16(kf0, qa[ks], st0, 0, 0, 0);
            st1 = __builtin_amdgcn_mfma_f32_32x32x16_bf16(kf1, qa[ks], st1, 0, 0, 0);
        }
        __builtin_amdgcn_s_setprio(0);

        bf16x8 pf[4];
        #pragma unroll
        for (int t = 0; t < 2; t++) {
            u32 pk[8];
            #pragma unroll
            for (int g = 0; g < 4; g++) {
                float p0 = ex2(t ? st1[4 * g + 0] : st0[4 * g + 0]);
                float p1 = ex2(t ? st1[4 * g + 1] : st0[4 * g + 1]);
                float p2 = ex2(t ? st1[4 * g + 2] : st0[4 * g + 2]);
                float p3 = ex2(t ? st1[4 * g + 3] : st0[4 * g + 3]);
                pk[2 * g + 0] = cvtpk(p0, p1);
                pk[2 * g + 1] = cvtpk(p2, p3);
            }
            u32 rA0 = __shfl_xor(half ? pk[0] : pk[2], 32);
            u32 rA1 = __shfl_xor(half ? pk[1] : pk[3], 32);
            u32 rB0 = __shfl_xor(half ? pk[4] : pk[6], 32);
            u32 rB1 = __shfl_xor(half ? pk[5] : pk[7], 32);
            u32x4 f0 = { half ? rA0 : pk[0], half ? rA1 : pk[1],
                         half ? pk[2] : rA0, half ? pk[3] : rA1 };
            u32x4 f1 = { half ? rB0 : pk[4], half ? rB1 : pk[5],
                         half ? pk[6] : rB0, half ? pk[7] : rB1 };
            union { u32x4 u; bf16x8 b; } c0{f0}, c1{f1};
            pf[2 * t + 0] = c0.b;
            pf[2 * t + 1] = c1.b;
        }

        __builtin_amdgcn_s_setprio(1);
        #pragma unroll
        for (int ks = 0; ks < 4; ks++) {
            bf16x8 v0f = *(const bf16x8*)&Vs[buf][(l32)      * 64 + fgo[ks]];
            bf16x8 v1f = *(const bf16x8*)&Vs[buf][(32 + l32) * 64 + fgo[ks]];
            lsum = __builtin_amdgcn_mfma_f32_32x32x16_bf16(pf[ks], ones, lsum, 0, 0, 0);
            o0   = __builtin_amdgcn_mfma_f32_32x32x16_bf16(pf[ks], v0f, o0, 0, 0, 0);
            o1   = __builtin_amdgcn_mfma_f32_32x32x16_bf16(pf[ks], v1f, o1, 0, 0, 0);
        }
        __builtin_amdgcn_s_setprio(0);
    }

    #pragma unroll
    for (int reg = 0; reg < 16; reg++) {
        float inv = 1.0f / lsum[reg];
        int row = (reg & 3) + 8 * (reg >> 2) + 4 * half;
        int qrow = qt * 128 + wave * 32 + row;
        size_t base = (size_t)(b * 1024 + qrow) * 768 + h * 64 + l32;
        ctx[base]      = f2bf(o0[reg] * inv);
        ctx[base + 32] = f2bf(o1[reg] * inv);
    }
}

// ---------------------------------------------------------------------------
extern "C" void kernel_launch(void* const* d_in, const int* in_sizes, int n_in,
                              void* d_out, int out_size, void* d_ws, size_t ws_size,
                              hipStream_t stream) {
    const float* x      = (const float*)d_in[0];  // [8,1024,768]
    const float* w_qkv  = (const float*)d_in[1];  // [768,2304]
    const float* w_proj = (const float*)d_in[2];  // [768,768]
    const float* b_proj = (const float*)d_in[3];  // [768]
    float* out = (float*)d_out;

    const int BN = 8192;     // B*N
    const int C = 768, C3 = 2304;
    const float CE = 0.18033688011112042f;  // 0.125 * log2(e)

    u16* Xb      = (u16*)d_ws;                       // 8192*768
    u16* Wqkv_t  = Xb + (size_t)BN * C;              // 2304*768
    u16* Wproj_t = Wqkv_t + (size_t)C3 * C;          // 768*768
    u16* QKV     = Wproj_t + (size_t)C * C;          // 8192*2304 (Q,K used)
    u16* Vt      = QKV + (size_t)BN * C3;            // 96*64*1024
    u16* Ctx     = Vt + (size_t)96 * 64 * 1024;      // 8192*768

    static bool s_attr = false;
    if (!s_attr) {
        (void)hipFuncSetAttribute((const void*)gemm_qkv<768>,
                                  hipFuncAttributeMaxDynamicSharedMemorySize, 147456);
        s_attr = true;
    }

    prep_all<<<8448, 256, 0, stream>>>(x, w_qkv, w_proj, Xb, Wqkv_t, Wproj_t);

    gemm_qkv<768><<<576, 512, 147456, stream>>>(Xb, Wqkv_t, QKV, Vt, CE);

    attn_kernel<<<dim3(8, 96), 256, 0, stream>>>(QKV, Vt, Ctx);

    gemm_proj<768><<<dim3(C / 128, BN / 128), 256, 0, stream>>>(
        Ctx, Wproj_t, out, b_proj, BN, C);
}

// Round 9
// 183.438 us; speedup vs baseline: 1.0740x; 1.0339x over previous
//
#include <hip/hip_runtime.h>

typedef __bf16 bf16x8 __attribute__((ext_vector_type(8)));
typedef float f32x4 __attribute__((ext_vector_type(4)));
typedef float f32x16 __attribute__((ext_vector_type(16)));
typedef unsigned short u16;
typedef unsigned int u32;
typedef u16 u16x4 __attribute__((ext_vector_type(4)));
typedef u32 u32x4 __attribute__((ext_vector_type(4)));

__device__ __forceinline__ u16 f2bf(float f) {
    union { float f; u32 u; } x{f};
    u32 r = x.u + 0x7FFFu + ((x.u >> 16) & 1u);  // RNE
    return (u16)(r >> 16);
}

__device__ __forceinline__ float ex2(float x) {
#if __has_builtin(__builtin_amdgcn_exp2f)
    return __builtin_amdgcn_exp2f(x);
#else
    return __expf(x * 0.6931471805599453f);
#endif
}

// packed f32 pair -> bf16x2 in one VALU op (RNE).
__device__ __forceinline__ u32 cvtpk(float a, float b) {
    u32 r;
    asm("v_cvt_pk_bf16_f32 %0, %1, %2" : "=v"(r) : "v"(a), "v"(b));
    return r;
}

// async global->LDS, 16B per lane; LDS dest = wave-uniform base + lane*16
#define GLD16(g, l)                                                            \
    __builtin_amdgcn_global_load_lds(                                          \
        (const __attribute__((address_space(1))) u32*)(g),                     \
        (__attribute__((address_space(3))) u32*)(l), 16, 0, 0)

// ---------------------------------------------------------------------------
// Merged prep: fp32->bf16 convert of x + both weight transposes.
// ---------------------------------------------------------------------------
__global__ __launch_bounds__(256) void prep_all(
    const float* __restrict__ x,
    const float* __restrict__ wq, const float* __restrict__ wp,
    u16* __restrict__ Xb,
    u16* __restrict__ WqT, u16* __restrict__ WpT)
{
    __shared__ u16 tile[32][33];
    int id = blockIdx.x;
    if (id < 6144) {
        int i = id * 256 + threadIdx.x;          // n4 = 8192*768/4 = 1572864 = 6144*256
        float4 f = *(const float4*)(x + (size_t)i * 4);
        u16x4 u = { f2bf(f.x), f2bf(f.y), f2bf(f.z), f2bf(f.w) };
        *(u16x4*)(Xb + (size_t)i * 4) = u;
        return;
    }
    id -= 6144;
    const float* src; u16* dst; int R, C, bx, by;
    if (id < 1728) { src = wq; dst = WqT; R = 768; C = 2304; bx = (id % 72) * 32; by = (id / 72) * 32; }
    else { id -= 1728; src = wp; dst = WpT; R = 768; C = 768; bx = (id % 24) * 32; by = (id / 24) * 32; }
    int xx = threadIdx.x & 31, yy = threadIdx.x >> 5;
    #pragma unroll
    for (int i = 0; i < 32; i += 8)
        tile[yy + i][xx] = f2bf(src[(size_t)(by + yy + i) * C + bx + xx]);
    __syncthreads();
    #pragma unroll
    for (int i = 0; i < 32; i += 8)
        dst[(size_t)(bx + yy + i) * R + by + xx] = tile[xx][yy + i];
}

// ---------------------------------------------------------------------------
// QKV GEMM, R9 (= R6 loop, best-measured twice): 256x128 tile, 512 thr /
// 8 waves of 64x64, 16x16x32 MFMA, conflict-free XOR-granule pattern,
// 3-buffer 144 KiB LDS, stage-ahead-2, counted vmcnt(6), 2-phase fine
// interleave with 2 barriers per phase.
// Grid 576 = 32 row-tiles x 18 col-tiles, XCD-chunked bijectively (8*72).
// V-section (bn>=1536) swaps MFMA operands -> Vt scatter.
// ---------------------------------------------------------------------------
#define MFMA16 __builtin_amdgcn_mfma_f32_16x16x32_bf16

#define STG_P0(tt)                                                              \
    {                                                                           \
        u16* ab_ = &lds[((tt) % 3) * 24576];                                    \
        GLD16(Ap + (tt) * 64 + (size_t)0 * 8 * K, &ab_[(wave * 32 + 0)  * 64]); \
        GLD16(Ap + (tt) * 64 + (size_t)1 * 8 * K, &ab_[(wave * 32 + 8)  * 64]); \
        GLD16(Ap + (tt) * 64 + (size_t)2 * 8 * K, &ab_[(wave * 32 + 16) * 64]); \
    }
#define STG_P1(tt)                                                              \
    {                                                                           \
        u16* ab_ = &lds[((tt) % 3) * 24576];                                    \
        GLD16(Ap + (tt) * 64 + (size_t)3 * 8 * K, &ab_[(wave * 32 + 24) * 64]); \
        GLD16(Bp + (tt) * 64 + (size_t)0 * 8 * K, &ab_[16384 + (wave * 16 + 0) * 64]); \
        GLD16(Bp + (tt) * 64 + (size_t)1 * 8 * K, &ab_[16384 + (wave * 16 + 8) * 64]); \
    }

template <int K>
__global__ __launch_bounds__(512, 1) void gemm_qkv(
    const u16* __restrict__ A,
    const u16* __restrict__ Wt,
    u16* __restrict__ QKV,
    u16* __restrict__ Vt,
    float qscale)
{
    extern __shared__ __align__(16) u16 lds[];   // 3 * (256*64 + 128*64) u16 = 144 KiB

    constexpr int NT = K / 64;   // 12 K-tiles

    int tid = threadIdx.x;
    int wave = tid >> 6, lane = tid & 63;
    int quad = lane >> 4, l16 = lane & 15;
    int wm = (wave >> 1) * 64;      // 4 M-waves: 0,64,128,192
    int wn = (wave & 1) * 64;       // 2 N-waves: 0,64

    int id = blockIdx.x;
    int lin = (id & 7) * 72 + (id >> 3);    // XCD-chunked, bijective (576 = 8*72)
    int bm = (lin / 18) * 256;              // 32 row-tiles
    int bn = (lin % 18) * 128;              // 18 col-tiles
    bool vsec = (bn >= 1536);

    f32x4 acc[4][4] = {};

    int srow = lane >> 3;
    int scg = ((lane & 7) ^ srow) * 8;
    const u16* Ap = A  + (size_t)(bm + wave * 32 + srow) * K + scg;
    const u16* Bp = Wt + (size_t)(bn + wave * 16 + srow) * K + scg;

    int fg0 = ((0 * 4 + quad) ^ (l16 & 7)) * 8;
    int fg1 = ((1 * 4 + quad) ^ (l16 & 7)) * 8;

    // prologue: stage tiles 0,1 (12 loads/thread); wait tile 0 (6 in flight)
    STG_P0(0); STG_P1(0);
    STG_P0(1); STG_P1(1);
    asm volatile("s_waitcnt vmcnt(6)" ::: "memory");
    __builtin_amdgcn_s_barrier();

    #pragma unroll 3
    for (int t = 0; t < NT; ++t) {
        const u16* Ab = &lds[(t % 3) * 24576];
        const u16* Bb = Ab + 16384;

        // ---- phase 0 (k-half 0): 8 ds_reads + 3 staging -> bar -> 16 MFMA -> bar
        {
            bf16x8 af[4], bfr[4];
            #pragma unroll
            for (int i = 0; i < 4; i++) {
                af[i]  = *(const bf16x8*)&Ab[(wm + i * 16 + l16) * 64 + fg0];
                bfr[i] = *(const bf16x8*)&Bb[(wn + i * 16 + l16) * 64 + fg0];
            }
            if (t + 2 < NT) STG_P0(t + 2);
            __builtin_amdgcn_s_barrier();
            __builtin_amdgcn_s_setprio(1);
            if (!vsec) {
                #pragma unroll
                for (int mi = 0; mi < 4; mi++)
                    #pragma unroll
                    for (int ni = 0; ni < 4; ni++)
                        acc[mi][ni] = MFMA16(af[mi], bfr[ni], acc[mi][ni], 0, 0, 0);
            } else {
                #pragma unroll
                for (int mi = 0; mi < 4; mi++)
                    #pragma unroll
                    for (int ni = 0; ni < 4; ni++)
                        acc[mi][ni] = MFMA16(bfr[ni], af[mi], acc[mi][ni], 0, 0, 0);
            }
            __builtin_amdgcn_s_setprio(0);
            __builtin_amdgcn_s_barrier();
        }

        // ---- phase 1 (k-half 1): 8 ds_reads + 3 staging -> bar -> 16 MFMA -> boundary
        {
            bf16x8 af[4], bfr[4];
            #pragma unroll
            for (int i = 0; i < 4; i++) {
                af[i]  = *(const bf16x8*)&Ab[(wm + i * 16 + l16) * 64 + fg1];
                bfr[i] = *(const bf16x8*)&Bb[(wn + i * 16 + l16) * 64 + fg1];
            }
            if (t + 2 < NT) STG_P1(t + 2);
            __builtin_amdgcn_s_barrier();
            __builtin_amdgcn_s_setprio(1);
            if (!vsec) {
                #pragma unroll
                for (int mi = 0; mi < 4; mi++)
                    #pragma unroll
                    for (int ni = 0; ni < 4; ni++)
                        acc[mi][ni] = MFMA16(af[mi], bfr[ni], acc[mi][ni], 0, 0, 0);
            } else {
                #pragma unroll
                for (int mi = 0; mi < 4; mi++)
                    #pragma unroll
                    for (int ni = 0; ni < 4; ni++)
                        acc[mi][ni] = MFMA16(bfr[ni], af[mi], acc[mi][ni], 0, 0, 0);
            }
            __builtin_amdgcn_s_setprio(0);
            // boundary: t+1's 6 loads must be done; t+2's 6 stay in flight
            if (t + 1 < NT) {
                if (t + 2 < NT) { asm volatile("s_waitcnt vmcnt(6)" ::: "memory"); }
                else            { asm volatile("s_waitcnt vmcnt(0)" ::: "memory"); }
            }
            __builtin_amdgcn_s_barrier();
        }
    }

    if (!vsec) {
        float sc = (bn < 768) ? qscale : 1.0f;   // col-tile is uniformly Q or K
        #pragma unroll
        for (int mi = 0; mi < 4; mi++) {
            #pragma unroll
            for (int ni = 0; ni < 4; ni++) {
                #pragma unroll
                for (int rg = 0; rg < 4; rg++) {
                    int row = bm + wm + mi * 16 + quad * 4 + rg;
                    int col = bn + wn + ni * 16 + l16;
                    QKV[(size_t)row * 2304 + col] = f2bf(acc[mi][ni][rg] * sc);
                }
            }
        }
    } else {
        #pragma unroll
        for (int mi = 0; mi < 4; mi++) {
            #pragma unroll
            for (int ni = 0; ni < 4; ni++) {
                #pragma unroll
                for (int rg = 0; rg < 4; rg++) {
                    int d = (bn - 1536) + wn + ni * 16 + quad * 4 + rg;
                    int ng = bm + wm + mi * 16 + l16;
                    int b = ng >> 10, n = ng & 1023, h = d >> 6;
                    Vt[((size_t)(b * 12 + h) * 64 + (d & 63)) * 1024 + n] = f2bf(acc[mi][ni][rg]);
                }
            }
        }
    }
}

#undef STG_P0
#undef STG_P1

// ---------------------------------------------------------------------------
// Output projection GEMM: R0-proven single-buffer 16x16 form (zero-conflict).
// ---------------------------------------------------------------------------
template <int K>
__global__ __launch_bounds__(256) void gemm_proj(
    const u16* __restrict__ A,
    const u16* __restrict__ Bt,
    float* __restrict__ Cp,
    const float* __restrict__ bias,
    int M, int N)
{
    __shared__ __align__(16) u16 As[128 * 64];
    __shared__ __align__(16) u16 Bs[128 * 64];

    int tid = threadIdx.x;
    int wave = tid >> 6, lane = tid & 63;
    int quad = lane >> 4, l16 = lane & 15;
    int wm = (wave >> 1) * 64, wn = (wave & 1) * 64;
    int bm = blockIdx.y * 128, bn = blockIdx.x * 128;

    f32x4 acc[4][4] = {};

    int srow = lane >> 3;
    int scg = ((lane & 7) ^ srow) * 8;
    const u16* Ap = A + (size_t)(bm + wave * 32 + srow) * K + scg;
    const u16* Bp = Bt + (size_t)(bn + wave * 32 + srow) * K + scg;

    int fg0 = (((0 * 4 + quad) ^ (l16 & 7)) * 8);
    int fg1 = (((1 * 4 + quad) ^ (l16 & 7)) * 8);

    for (int k0 = 0; k0 < K; k0 += 64) {
        #pragma unroll
        for (int j = 0; j < 4; j++) {
            GLD16(Ap + k0 + (size_t)j * 8 * K, &As[(wave * 32 + j * 8) * 64]);
            GLD16(Bp + k0 + (size_t)j * 8 * K, &Bs[(wave * 32 + j * 8) * 64]);
        }
        __syncthreads();

        #pragma unroll
        for (int h = 0; h < 2; h++) {
            int fg = h ? fg1 : fg0;
            bf16x8 af[4], bfr[4];
            #pragma unroll
            for (int i = 0; i < 4; i++) {
                af[i]  = *(const bf16x8*)&As[(wm + i * 16 + l16) * 64 + fg];
                bfr[i] = *(const bf16x8*)&Bs[(wn + i * 16 + l16) * 64 + fg];
            }
            #pragma unroll
            for (int mi = 0; mi < 4; mi++)
                #pragma unroll
                for (int ni = 0; ni < 4; ni++)
                    acc[mi][ni] = __builtin_amdgcn_mfma_f32_16x16x32_bf16(af[mi], bfr[ni], acc[mi][ni], 0, 0, 0);
        }
        __syncthreads();
    }

    #pragma unroll
    for (int mi = 0; mi < 4; mi++) {
        #pragma unroll
        for (int ni = 0; ni < 4; ni++) {
            #pragma unroll
            for (int rg = 0; rg < 4; rg++) {
                int row = bm + wm + mi * 16 + quad * 4 + rg;
                int col = bn + wn + ni * 16 + l16;
                Cp[(size_t)row * N + col] = acc[mi][ni][rg] + bias[col];
            }
        }
    }
}

// ---------------------------------------------------------------------------
// Flash attention v4, R9: XCD-affinity swizzle. The 8 qt-blocks sharing one
// (b,h)'s 256 KB K/V previously round-robined across 8 XCDs (each XCD
// fetching its own copy, ~8x L2-miss traffic). Now XCD x (= id&7) owns
// bh in [12x, 12x+12): its 96 blocks are fully co-resident (32 CU x 3) and
// their 12 x 256 KB = 3 MB K/V working set fits the 4 MB per-XCD L2.
// (256,3) launch bounds + cvt_pk packing retained from R8.
// ---------------------------------------------------------------------------
__global__ __launch_bounds__(256, 3) void attn_kernel(
    const u16* __restrict__ qkv,
    const u16* __restrict__ Vt,
    u16* __restrict__ ctx)
{
    __shared__ __align__(16) u16 Ks[2][4096];   // 2 x 64key x 64d (swizzled)
    __shared__ __align__(16) u16 Vs[2][4096];   // 2 x 64d x 64key (swizzled)

    int id = blockIdx.x;            // 0..767
    int xcd = id & 7;
    int pos = id >> 3;              // 0..95
    int bh = xcd * 12 + (pos >> 3); // 12 bh per XCD
    int qt = pos & 7;               // 8 q-tiles per bh
    int b = bh / 12, h = bh % 12;
    int tid = threadIdx.x;
    int wave = tid >> 6, lane = tid & 63;
    int l32 = lane & 31, half = lane >> 5;

    const u16* qbase = qkv + (size_t)(b * 1024 + qt * 128 + wave * 32 + l32) * 2304 + h * 64;
    bf16x8 qa[4];
    #pragma unroll
    for (int ks = 0; ks < 4; ks++)
        qa[ks] = *(const bf16x8*)(qbase + ks * 16 + half * 8);

    int srow = lane >> 3;
    int scol = (lane & 7) ^ srow;
    const u16* kA = qkv + (size_t)(b * 1024 + wave * 16 + srow) * 2304 + 768 + h * 64 + scol * 8;
    const u16* vA = Vt + ((size_t)bh * 64 + wave * 16 + srow) * 1024 + scol * 8;

    bf16x8 ones;
    #pragma unroll
    for (int j = 0; j < 8; j++) ((u16*)&ones)[j] = 0x3F80;  // bf16 1.0

    f32x16 o0 = {}, o1 = {}, lsum = {};

    int fgo[4];
    #pragma unroll
    for (int ks = 0; ks < 4; ks++)
        fgo[ks] = (((ks * 2 + half) ^ (lane & 7)) * 8);

    {
        GLD16(kA,            &Ks[0][(wave * 2 + 0) * 512]);
        GLD16(kA + 8 * 2304, &Ks[0][(wave * 2 + 1) * 512]);
        GLD16(vA,            &Vs[0][(wave * 2 + 0) * 512]);
        GLD16(vA + 8 * 1024, &Vs[0][(wave * 2 + 1) * 512]);
    }

    #pragma unroll 2
    for (int kt = 0; kt < 16; kt++) {
        int buf = kt & 1;
        __syncthreads();   // drains vmcnt(0): buf is populated

        if (kt < 15) {
            const u16* k0 = kA + (size_t)(kt + 1) * (64 * 2304);
            const u16* v0 = vA + (size_t)(kt + 1) * 64;
            GLD16(k0,            &Ks[buf ^ 1][(wave * 2 + 0) * 512]);
            GLD16(k0 + 8 * 2304, &Ks[buf ^ 1][(wave * 2 + 1) * 512]);
            GLD16(v0,            &Vs[buf ^ 1][(wave * 2 + 0) * 512]);
            GLD16(v0 + 8 * 1024, &Vs[buf ^ 1][(wave * 2 + 1) * 512]);
        }

        f32x16 st0 = {}, st1 = {};
        __builtin_amdgcn_s_setprio(1);
        #pragma unroll
        for (int ks = 0; ks < 4; ks++) {
            bf16x8 kf0 = *(const bf16x8*)&Ks[buf][(l32)      * 64 + fgo[ks]];
            bf16x8 kf1 = *(const bf16x8*)&Ks[buf][(32 + l32) * 64 + fgo[ks]];
            st0 = __builtin_amdgcn_mfma_f32_32x32x16_bf16(kf0, qa[ks], st0, 0, 0, 0);
            st1 = __builtin_amdgcn_mfma_f32_32x32x16_bf16(kf1, qa[ks], st1, 0, 0, 0);
        }
        __builtin_amdgcn_s_setprio(0);

        bf16x8 pf[4];
        #pragma unroll
        for (int t = 0; t < 2; t++) {
            u32 pk[8];
            #pragma unroll
            for (int g = 0; g < 4; g++) {
                float p0 = ex2(t ? st1[4 * g + 0] : st0[4 * g + 0]);
                float p1 = ex2(t ? st1[4 * g + 1] : st0[4 * g + 1]);
                float p2 = ex2(t ? st1[4 * g + 2] : st0[4 * g + 2]);
                float p3 = ex2(t ? st1[4 * g + 3] : st0[4 * g + 3]);
                pk[2 * g + 0] = cvtpk(p0, p1);
                pk[2 * g + 1] = cvtpk(p2, p3);
            }
            u32 rA0 = __shfl_xor(half ? pk[0] : pk[2], 32);
            u32 rA1 = __shfl_xor(half ? pk[1] : pk[3], 32);
            u32 rB0 = __shfl_xor(half ? pk[4] : pk[6], 32);
            u32 rB1 = __shfl_xor(half ? pk[5] : pk[7], 32);
            u32x4 f0 = { half ? rA0 : pk[0], half ? rA1 : pk[1],
                         half ? pk[2] : rA0, half ? pk[3] : rA1 };
            u32x4 f1 = { half ? rB0 : pk[4], half ? rB1 : pk[5],
                         half ? pk[6] : rB0, half ? pk[7] : rB1 };
            union { u32x4 u; bf16x8 b; } c0{f0}, c1{f1};
            pf[2 * t + 0] = c0.b;
            pf[2 * t + 1] = c1.b;
        }

        __builtin_amdgcn_s_setprio(1);
        #pragma unroll
        for (int ks = 0; ks < 4; ks++) {
            bf16x8 v0f = *(const bf16x8*)&Vs[buf][(l32)      * 64 + fgo[ks]];
            bf16x8 v1f = *(const bf16x8*)&Vs[buf][(32 + l32) * 64 + fgo[ks]];
            lsum = __builtin_amdgcn_mfma_f32_32x32x16_bf16(pf[ks], ones, lsum, 0, 0, 0);
            o0   = __builtin_amdgcn_mfma_f32_32x32x16_bf16(pf[ks], v0f, o0, 0, 0, 0);
            o1   = __builtin_amdgcn_mfma_f32_32x32x16_bf16(pf[ks], v1f, o1, 0, 0, 0);
        }
        __builtin_amdgcn_s_setprio(0);
    }

    #pragma unroll
    for (int reg = 0; reg < 16; reg++) {
        float inv = 1.0f / lsum[reg];
        int row = (reg & 3) + 8 * (reg >> 2) + 4 * half;
        int qrow = qt * 128 + wave * 32 + row;
        size_t base = (size_t)(b * 1024 + qrow) * 768 + h * 64 + l32;
        ctx[base]      = f2bf(o0[reg] * inv);
        ctx[base + 32] = f2bf(o1[reg] * inv);
    }
}

// ---------------------------------------------------------------------------
extern "C" void kernel_launch(void* const* d_in, const int* in_sizes, int n_in,
                              void* d_out, int out_size, void* d_ws, size_t ws_size,
                              hipStream_t stream) {
    const float* x      = (const float*)d_in[0];  // [8,1024,768]
    const float* w_qkv  = (const float*)d_in[1];  // [768,2304]
    const float* w_proj = (const float*)d_in[2];  // [768,768]
    const float* b_proj = (const float*)d_in[3];  // [768]
    float* out = (float*)d_out;

    const int BN = 8192;     // B*N
    const int C = 768, C3 = 2304;
    const float CE = 0.18033688011112042f;  // 0.125 * log2(e)

    u16* Xb      = (u16*)d_ws;                       // 8192*768
    u16* Wqkv_t  = Xb + (size_t)BN * C;              // 2304*768
    u16* Wproj_t = Wqkv_t + (size_t)C3 * C;          // 768*768
    u16* QKV     = Wproj_t + (size_t)C * C;          // 8192*2304 (Q,K used)
    u16* Vt      = QKV + (size_t)BN * C3;            // 96*64*1024
    u16* Ctx     = Vt + (size_t)96 * 64 * 1024;      // 8192*768

    static bool s_attr = false;
    if (!s_attr) {
        (void)hipFuncSetAttribute((const void*)gemm_qkv<768>,
                                  hipFuncAttributeMaxDynamicSharedMemorySize, 147456);
        s_attr = true;
    }

    prep_all<<<8448, 256, 0, stream>>>(x, w_qkv, w_proj, Xb, Wqkv_t, Wproj_t);

    gemm_qkv<768><<<576, 512, 147456, stream>>>(Xb, Wqkv_t, QKV, Vt, CE);

    attn_kernel<<<768, 256, 0, stream>>>(QKV, Vt, Ctx);

    gemm_proj<768><<<dim3(C / 128, BN / 128), 256, 0, stream>>>(
        Ctx, Wproj_t, out, b_proj, BN, C);
}